// Round 3
// baseline (320.018 us; speedup 1.0000x reference)
//
#include <hip/hip_runtime.h>
#include <math.h>
#include <float.h>

// VectorQuantize, screen-and-rescore:
//  pass1: fp16 hH MFMA screen + per-row top-3 -> certified rows rescored exact fp32
//  pass2: suspect rows (m3-m1 <= THR) get a full exact fp32 scan (round-1 formula).
// x [65536,64] f32, codebook [4096,64] f32.
// d_out (flat f32): quantized [N*64], idx [N] (as float), min_dists [N].

#define NROWS 65536
#define CDIM  64
#define KCB   4096
#define THR   0.0625f   // >= 2*max screen error (sigma~1.6e-3, 39-sigma margin)

typedef _Float16 half8 __attribute__((ext_vector_type(8)));
typedef _Float16 half4 __attribute__((ext_vector_type(4)));
typedef float f32x4 __attribute__((ext_vector_type(4)));

#define MFMA16(A, B, C) __builtin_amdgcn_mfma_f32_16x16x32_f16(A, B, C, 0, 0, 0)

__device__ __forceinline__ void top3_insert(float d, int k, float& m1, int& i1,
                                            float& m2, int& i2, float& m3) {
    const bool t1 = d < m1, t2 = d < m2, t3 = d < m3;
    m3 = t2 ? m2 : (t3 ? d : m3);
    m2 = t1 ? m1 : (t2 ? d : m2);
    i2 = t1 ? i1 : (t2 ? k : i2);
    m1 = t1 ? d : m1;
    i1 = t1 ? k : i1;
}

// Exact fp32 distance, byte-identical arithmetic to the round-1 kernel that
// matched np with absmax 0 (2-chain fma dot, fmaf(-2,dot,x2)+c2).
__device__ __forceinline__ float exact_d2(const float* __restrict__ xr, const float* __restrict__ cb,
                                          const float* __restrict__ c2f, float x2, int k) {
    const float4* cp4 = reinterpret_cast<const float4*>(cb + (size_t)k * CDIM);
    float da = 0.f, db = 0.f;
#pragma unroll
    for (int j4 = 0; j4 < CDIM / 4; ++j4) {
        float4 cv = cp4[j4];
        da = fmaf(xr[4 * j4 + 0], cv.x, da);
        db = fmaf(xr[4 * j4 + 1], cv.y, db);
        da = fmaf(xr[4 * j4 + 2], cv.z, da);
        db = fmaf(xr[4 * j4 + 3], cv.w, db);
    }
    const float dot = da + db;
    return fmaf(-2.f, dot, x2) + c2f[k];
}

// ---- prep: fp16 codebook + c2f = ||c_k||^2 + zero suspect counter ----
__global__ __launch_bounds__(256) void prep_cb(const float* __restrict__ cb,
                                               _Float16* __restrict__ ch,
                                               float* __restrict__ c2f,
                                               int* __restrict__ cnt) {
    if (blockIdx.x == 0 && threadIdx.x == 0) *cnt = 0;
    const int row = blockIdx.x * 16 + (threadIdx.x >> 4);
    const int j   = threadIdx.x & 15;
    const float4 v = *reinterpret_cast<const float4*>(cb + (size_t)row * CDIM + j * 4);
    float s;
    {
#pragma clang fp contract(off)
        s = v.x * v.x + v.y * v.y + v.z * v.z + v.w * v.w;
    }
    s += __shfl_xor(s, 1);
    s += __shfl_xor(s, 2);
    s += __shfl_xor(s, 4);
    s += __shfl_xor(s, 8);
    if (j == 0) c2f[row] = s;
    half4 h;
#pragma unroll
    for (int t = 0; t < 4; ++t) h[t] = (_Float16)(t == 0 ? v.x : t == 1 ? v.y : t == 2 ? v.z : v.w);
    *reinterpret_cast<half4*>(ch + (size_t)row * CDIM + j * 4) = h;
}

// ---- pass 1: screen + top-3 + rescore/certify ----
__global__ __launch_bounds__(256, 2) void vq_screen(
    const float* __restrict__ x, const float* __restrict__ cb,
    const _Float16* __restrict__ ch, const float* __restrict__ c2f,
    float* __restrict__ outq, float* __restrict__ outidx, float* __restrict__ outd,
    int* __restrict__ cnt, int* __restrict__ suspects) {

    const int tid  = threadIdx.x;
    const int lane = tid & 63;
    const int wv   = __builtin_amdgcn_readfirstlane(tid >> 6);
    const int lrow = lane & 15;
    const int lhi  = lane >> 4;
    const int n0   = blockIdx.x * 64;
    const int kbase = wv * 1024;   // each wave screens a k-quarter

    // A fragments (x rows n0..n0+63, layout proven in round 2)
    half8 afh[4][2];
#pragma unroll
    for (int st = 0; st < 4; ++st) {
#pragma unroll
        for (int cs = 0; cs < 2; ++cs) {
            const float* xp = x + (size_t)(n0 + st * 16 + lrow) * CDIM + cs * 32 + lhi * 8;
            const float4 a = *reinterpret_cast<const float4*>(xp);
            const float4 b = *reinterpret_cast<const float4*>(xp + 4);
            float e[8] = {a.x, a.y, a.z, a.w, b.x, b.y, b.z, b.w};
#pragma unroll
            for (int jj = 0; jj < 8; ++jj) afh[st][cs][jj] = (_Float16)e[jj];
        }
    }

    float sm1[4][4], sm2[4][4], sm3[4][4];
    int   si1[4][4], si2[4][4];
#pragma unroll
    for (int st = 0; st < 4; ++st)
#pragma unroll
        for (int r = 0; r < 4; ++r) {
            sm1[st][r] = FLT_MAX; sm2[st][r] = FLT_MAX; sm3[st][r] = FLT_MAX;
            si1[st][r] = 0; si2[st][r] = 0;
        }

    const _Float16* pb  = ch + (size_t)(kbase + lrow) * CDIM + lhi * 8;
    const float*    pc2 = c2f + kbase + lrow;

    for (int kt = 0; kt < 64; ++kt) {
        const half8 bh0 = *reinterpret_cast<const half8*>(pb + kt * 1024);
        const half8 bh1 = *reinterpret_cast<const half8*>(pb + kt * 1024 + 32);
        const float c2k = pc2[kt * 16];
        const int   kv  = kbase + kt * 16 + lrow;

        f32x4 acc[4];
#pragma unroll
        for (int st = 0; st < 4; ++st) acc[st] = (f32x4)0.f;
#pragma unroll
        for (int st = 0; st < 4; ++st) acc[st] = MFMA16(afh[st][0], bh0, acc[st]);
#pragma unroll
        for (int st = 0; st < 4; ++st) acc[st] = MFMA16(afh[st][1], bh1, acc[st]);

#pragma unroll
        for (int st = 0; st < 4; ++st)
#pragma unroll
            for (int r = 0; r < 4; ++r) {
                const float dd = fmaf(-2.f, acc[st][r], c2k);  // d2 - x2
                top3_insert(dd, kv, sm1[st][r], si1[st][r], sm2[st][r], si2[st][r], sm3[st][r]);
            }
    }

    // butterfly-merge the 16 k-slice lanes (lrow) of each lhi group
#pragma unroll
    for (int st = 0; st < 4; ++st)
#pragma unroll
        for (int r = 0; r < 4; ++r) {
#pragma unroll
            for (int msk = 1; msk <= 8; msk <<= 1) {
                const float om1 = __shfl_xor(sm1[st][r], msk);
                const int   oi1 = __shfl_xor(si1[st][r], msk);
                const float om2 = __shfl_xor(sm2[st][r], msk);
                const int   oi2 = __shfl_xor(si2[st][r], msk);
                const float om3 = __shfl_xor(sm3[st][r], msk);
                top3_insert(om1, oi1, sm1[st][r], si1[st][r], sm2[st][r], si2[st][r], sm3[st][r]);
                top3_insert(om2, oi2, sm1[st][r], si1[st][r], sm2[st][r], si2[st][r], sm3[st][r]);
                sm3[st][r] = fminf(sm3[st][r], om3);
            }
        }

    __shared__ float Lm1[4][64], Lm2[4][64], Lm3[4][64];
    __shared__ int   Li1[4][64], Li2[4][64];
    __shared__ int   Lwin[64];
#pragma unroll
    for (int st = 0; st < 4; ++st)
#pragma unroll
        for (int r = 0; r < 4; ++r)
            if (lrow == st * 4 + r) {
                const int rw = st * 16 + lhi * 4 + r;
                Lm1[wv][rw] = sm1[st][r]; Li1[wv][rw] = si1[st][r];
                Lm2[wv][rw] = sm2[st][r]; Li2[wv][rw] = si2[st][r];
                Lm3[wv][rw] = sm3[st][r];
            }
    __syncthreads();

    if (tid < 64) {
        float m1 = Lm1[0][tid]; int i1 = Li1[0][tid];
        float m2 = Lm2[0][tid]; int i2 = Li2[0][tid];
        float m3 = Lm3[0][tid];
#pragma unroll
        for (int w = 1; w < 4; ++w) {
            top3_insert(Lm1[w][tid], Li1[w][tid], m1, i1, m2, i2, m3);
            top3_insert(Lm2[w][tid], Li2[w][tid], m1, i1, m2, i2, m3);
            m3 = fminf(m3, Lm3[w][tid]);
        }
        const int row = n0 + tid;

        // exact rescore of {i1, i2}
        float xr[CDIM];
        const float4* xp = reinterpret_cast<const float4*>(x + (size_t)row * CDIM);
#pragma unroll
        for (int j = 0; j < CDIM / 4; ++j) {
            const float4 v = xp[j];
            xr[4 * j + 0] = v.x; xr[4 * j + 1] = v.y;
            xr[4 * j + 2] = v.z; xr[4 * j + 3] = v.w;
        }
        float x2 = 0.f;
        {
#pragma clang fp contract(off)
#pragma unroll
            for (int j = 0; j < CDIM; ++j) x2 += xr[j] * xr[j];
        }
        const float d2a = exact_d2(xr, cb, c2f, x2, i1);
        const float d2b = exact_d2(xr, cb, c2f, x2, i2);
        int win; float d2w;
        if (d2b < d2a || (d2b == d2a && i2 < i1)) { win = i2; d2w = d2b; }
        else                                      { win = i1; d2w = d2a; }

        if (!(m3 - m1 > THR)) {            // not certified -> exact rescan later
            const int s = atomicAdd(cnt, 1);
            suspects[s] = row;
        }
        outidx[row] = (float)win;          // provisional for suspects; vq_fix overwrites
        outd[row]   = sqrtf(fmaxf(d2w, 0.f));
        Lwin[tid]   = win;
    }
    __syncthreads();

    // gather quantized = codebook[win]
    {
        const int r   = tid >> 2;
        const int seg = tid & 3;
        const int b   = Lwin[r];
        const float4* src = reinterpret_cast<const float4*>(cb + (size_t)b * CDIM) + seg * 4;
        float4* dst = reinterpret_cast<float4*>(outq + (size_t)(n0 + r) * CDIM) + seg * 4;
#pragma unroll
        for (int t = 0; t < 4; ++t) dst[t] = src[t];
    }
}

// ---- pass 2: exact fp32 full scan for suspect rows ----
__global__ __launch_bounds__(256, 2) void vq_fix(
    const float* __restrict__ x, const float* __restrict__ cb, const float* __restrict__ c2f,
    const int* __restrict__ cnt, const int* __restrict__ suspects,
    float* __restrict__ outq, float* __restrict__ outidx, float* __restrict__ outd) {

    const int count = *cnt;
    const int lane  = threadIdx.x & 63;
    const int gw    = blockIdx.x * 4 + (threadIdx.x >> 6);
    const int nw    = gridDim.x * 4;

    for (int s = gw; s < count; s += nw) {
        const int row = suspects[s];
        float xr[CDIM];
        const float4* xp = reinterpret_cast<const float4*>(x + (size_t)row * CDIM);
#pragma unroll
        for (int j = 0; j < CDIM / 4; ++j) {
            const float4 v = xp[j];
            xr[4 * j + 0] = v.x; xr[4 * j + 1] = v.y;
            xr[4 * j + 2] = v.z; xr[4 * j + 3] = v.w;
        }
        float x2 = 0.f;
        {
#pragma clang fp contract(off)
#pragma unroll
            for (int j = 0; j < CDIM; ++j) x2 += xr[j] * xr[j];
        }
        float bd = FLT_MAX;
        int   bi = 0;
        for (int j = 0; j < KCB / 64; ++j) {
            const int k = j * 64 + lane;                 // ascending per lane
            const float d2 = exact_d2(xr, cb, c2f, x2, k);
            if (d2 < bd) { bd = d2; bi = k; }            // strict <: first index
        }
#pragma unroll
        for (int msk = 1; msk <= 32; msk <<= 1) {
            const float od = __shfl_xor(bd, msk);
            const int   oi = __shfl_xor(bi, msk);
            if (od < bd || (od == bd && oi < bi)) { bd = od; bi = oi; }
        }
        if (lane == 0) {
            outidx[row] = (float)bi;
            outd[row]   = sqrtf(fmaxf(bd, 0.f));
        }
        outq[(size_t)row * CDIM + lane] = cb[(size_t)bi * CDIM + lane];
    }
}

extern "C" void kernel_launch(void* const* d_in, const int* in_sizes, int n_in,
                              void* d_out, int out_size, void* d_ws, size_t ws_size,
                              hipStream_t stream) {
    const float* x  = (const float*)d_in[0];
    const float* cb = (const float*)d_in[1];
    float* outq   = (float*)d_out;
    float* outidx = outq + (size_t)NROWS * CDIM;
    float* outd   = outidx + NROWS;

    char* ws = (char*)d_ws;
    _Float16* ch  = (_Float16*)ws;                       // 512 KB
    float*    c2f = (float*)(ws + 512 * 1024);           // 16 KB
    int*      cnt = (int*)(ws + 528 * 1024);             // 4 B (padded to 256)
    int*      sus = (int*)(ws + 528 * 1024 + 256);       // 256 KB

    prep_cb<<<KCB / 16, 256, 0, stream>>>(cb, ch, c2f, cnt);
    vq_screen<<<NROWS / 64, 256, 0, stream>>>(x, cb, ch, c2f, outq, outidx, outd, cnt, sus);
    vq_fix<<<512, 256, 0, stream>>>(x, cb, c2f, cnt, sus, outq, outidx, outd);
}